// Round 2
// baseline (514.971 us; speedup 1.0000x reference)
//
#include <hip/hip_runtime.h>
#include <hip/hip_bf16.h>
#include <stdint.h>

#define B_ 8
#define M_ 2048
#define N_ 2048
#define D_ 1024

typedef __bf16 bf16x8 __attribute__((ext_vector_type(8)));
typedef float f32x4 __attribute__((ext_vector_type(4)));
typedef uint16_t us4 __attribute__((ext_vector_type(4)));
typedef uint16_t us8 __attribute__((ext_vector_type(8)));

__device__ __forceinline__ uint16_t f2b(float f) {
    uint32_t u = __float_as_uint(f);
    return (uint16_t)((u + 0x7FFFu + ((u >> 16) & 1u)) >> 16);
}
__device__ __forceinline__ float b2f(uint16_t h) {
    return __uint_as_float(((uint32_t)h) << 16);
}

__device__ __forceinline__ void gld16(const uint16_t* g, const uint16_t* l) {
    __builtin_amdgcn_global_load_lds(
        (const __attribute__((address_space(1))) uint32_t*)g,
        (__attribute__((address_space(3))) uint32_t*)l,
        16, 0, 0);
}

// ---------------- split x,y into bf16 hi/lo ----------------
__global__ __launch_bounds__(256) void k_split(const float* __restrict__ x,
                                               const float* __restrict__ y,
                                               uint16_t* __restrict__ xh, uint16_t* __restrict__ xl,
                                               uint16_t* __restrict__ yh, uint16_t* __restrict__ yl) {
    const int i = (blockIdx.x * 256 + threadIdx.x) * 4;
    float4 vx = *(const float4*)(x + i);
    float4 vy = *(const float4*)(y + i);
    float fx[4] = {vx.x, vx.y, vx.z, vx.w};
    float fy[4] = {vy.x, vy.y, vy.z, vy.w};
    us4 hx, lx, hy, ly;
#pragma unroll
    for (int k = 0; k < 4; ++k) {
        uint16_t h = f2b(fx[k]);
        hx[k] = h; lx[k] = f2b(fx[k] - b2f(h));
        uint16_t g = f2b(fy[k]);
        hy[k] = g; ly[k] = f2b(fy[k] - b2f(g));
    }
    *(us4*)(xh + i) = hx;
    *(us4*)(xl + i) = lx;
    *(us4*)(yh + i) = hy;
    *(us4*)(yl + i) = ly;
}

// ---------------- GEMM1: e = A'.B'^T, A'=[xh|xh|xl], B'=[yh|yl|yh], K=3072 ----------------
// m201 8-phase template: 256x256 tile, 8 waves (2Mx4N, wave tile 128x64), BK=64,
// 2 LDS buffers (A 32KB + B 32KB each, 128KB total). Iteration = 2 K-tiles,
// 8 phases; each phase = 1 quadrant (2 i-tiles x 4 j x 2 khalf = 16 MFMA).
// B-fragments are register-cached across the 4 quadrant phases -> B-halves of a
// buffer are dead after phase 1/5 and restaged 6-7 phases ahead; A-halves dead
// after phase 4/8, restaged 3-4 phases ahead. Counted s_waitcnt vmcnt(4) ONLY
// at phases 4 and 8 (3 half-tiles in flight, never drained mid-loop);
// wait-then-barrier orders cross-wave staging.
// LDS swizzle (BK=64, 8x16B granules/row): granule g of row r at pos g^(r&7)
// (gemm2's measured-0-conflict scheme).
// Epilogue: e tile + per-(row, 64-col) softmax partials (max, sum-exp).
#define BAR1 do { __builtin_amdgcn_sched_barrier(0); __builtin_amdgcn_s_barrier(); \
                  __builtin_amdgcn_sched_barrier(0); } while (0)
#define LD8(off) (*(const bf16x8*)&lds[off])
#define RDA(bo32, q)                                                   \
    a[0][0] = LD8((bo32) + aoff + ((q)*2) * 1024 + e0);                \
    a[0][1] = LD8((bo32) + aoff + ((q)*2) * 1024 + e1);                \
    a[1][0] = LD8((bo32) + aoff + ((q)*2 + 1) * 1024 + e0);            \
    a[1][1] = LD8((bo32) + aoff + ((q)*2 + 1) * 1024 + e1);
#define RDB(bo32)                                                      \
    _Pragma("unroll") for (int j = 0; j < 4; ++j) {                    \
        bb[j][0] = LD8((bo32) + boff + j * 1024 + e0);                 \
        bb[j][1] = LD8((bo32) + boff + j * 1024 + e1);                 \
    }
#define MFMA16(q)                                                      \
    __builtin_amdgcn_s_setprio(1);                                     \
    _Pragma("unroll") for (int kh = 0; kh < 2; ++kh)                   \
    _Pragma("unroll") for (int ii = 0; ii < 2; ++ii)                   \
    _Pragma("unroll") for (int j = 0; j < 4; ++j)                      \
        acc[(q)*2 + ii][j] = __builtin_amdgcn_mfma_f32_16x16x32_bf16(  \
            a[ii][kh], bb[j][kh], acc[(q)*2 + ii][j], 0, 0, 0);        \
    __builtin_amdgcn_s_setprio(0);

__global__ __launch_bounds__(512, 2) void k_gemm1(const uint16_t* __restrict__ xh,
                                                  const uint16_t* __restrict__ xl,
                                                  const uint16_t* __restrict__ yh,
                                                  const uint16_t* __restrict__ yl,
                                                  float* __restrict__ e,
                                                  float* __restrict__ pmax,
                                                  float* __restrict__ psum) {
    const int b = blockIdx.z;
    const int m0 = blockIdx.x * 256;
    const int n0 = blockIdx.y * 256;
    __shared__ __align__(16) uint16_t lds[65536];  // 2 buf x (A 16384 + B 16384)

    const int tid = threadIdx.x;
    const int lane = tid & 63;
    const int wid = tid >> 6;             // 8 waves: 2 (m) x 4 (n)
    const int wm = (wid >> 2) * 128;
    const int wn = (wid & 3) * 64;
    const int quad = lane >> 4;
    const int r16 = lane & 15;
    const int rb7 = r16 & 7;
    const int e0 = (quad ^ rb7) * 8;          // khalf 0 granule position
    const int e1 = ((quad + 4) ^ rb7) * 8;    // khalf 1
    const int aoff = (wm + r16) * 64;
    const int boff = 16384 + (wn + r16) * 64;

    // staging: per round 512 thr x 16B = 64 rows x 128B; srow = tid>>3,
    // granule gp = tid&7, source granule gd = gp ^ (srow&7)  (swizzle inverse)
    const int srow = tid >> 3;
    const int gd8 = ((tid & 7) ^ ((tid >> 3) & 7)) * 8;

    auto Ab = [&](int kt) {  // A' region: kt<32 -> xh, else xl; k0 = (kt&15)*64
        return (kt < 32 ? xh : xl) + ((size_t)b * M_ + m0) * D_ + (kt & 15) * 64 + gd8;
    };
    auto Bb = [&](int kt) {  // B' region: [yh | yl | yh]
        return (((kt >> 4) == 1) ? yl : yh) + ((size_t)b * N_ + n0) * D_ + (kt & 15) * 64 + gd8;
    };
    auto SH = [&](int dst, const uint16_t* srcb, int h) {  // one half-tile (128 rows)
        gld16(srcb + (size_t)(h * 128 + srow) * D_, &lds[dst + h * 8192 + wid * 512]);
        gld16(srcb + (size_t)(h * 128 + 64 + srow) * D_, &lds[dst + h * 8192 + 4096 + wid * 512]);
    };

    f32x4 acc[8][4];
#pragma unroll
    for (int i = 0; i < 8; ++i)
#pragma unroll
        for (int j = 0; j < 4; ++j) acc[i][j] = (f32x4){0.f, 0.f, 0.f, 0.f};

    bf16x8 a[2][2], bb[4][2];

    // prologue: buf0 <- kt0 (A+B), buf1 <- B(kt1). A(kt1) staged in iter0 ph1/2.
    SH(0, Ab(0), 0); SH(0, Ab(0), 1);
    SH(16384, Bb(0), 0); SH(16384, Bb(0), 1);
    SH(49152, Bb(1), 0); SH(49152, Bb(1), 1);
    asm volatile("s_waitcnt vmcnt(4)" ::: "memory");  // buf0 complete; B(kt1) flies
    __builtin_amdgcn_s_barrier();
    __builtin_amdgcn_sched_barrier(0);

    for (int t = 0; t < 24; ++t) {
        const bool s2 = t < 23;
        const uint16_t* a1p = Ab(2 * t + 1);
        const uint16_t* a2p = Ab(2 * t + 2);
        const uint16_t* b2p = Bb(2 * t + 2);
        const uint16_t* b3p = Bb(2 * t + 3);

        // ---- phases 1-4: compute kt0=2t from buf0 (base 0)
        RDB(0); RDA(0, 0);
        SH(32768, a1p, 0);                       // buf1A <- A(2t+1) half0
        BAR1; MFMA16(0); BAR1;

        RDA(0, 1);
        SH(32768, a1p, 1);                       // buf1A half1
        if (s2) SH(16384, b2p, 0);               // buf0B <- B(2t+2) half0 (dead after ph1)
        BAR1; MFMA16(1); BAR1;

        RDA(0, 2);
        if (s2) SH(16384, b2p, 1);
        BAR1; MFMA16(2); BAR1;

        RDA(0, 3);
        BAR1; MFMA16(3);
        if (s2) { asm volatile("s_waitcnt vmcnt(4)" ::: "memory"); }   // A(2t+1) landed
        else    { asm volatile("s_waitcnt vmcnt(0)" ::: "memory"); }
        BAR1;

        // ---- phases 5-8: compute kt1=2t+1 from buf1 (base 32768)
        RDB(32768); RDA(32768, 0);
        if (s2) SH(0, a2p, 0);                   // buf0A <- A(2t+2) (dead after ph4)
        BAR1; MFMA16(0); BAR1;

        RDA(32768, 1);
        if (s2) { SH(0, a2p, 1); SH(49152, b3p, 0); }  // buf1B <- B(2t+3) (dead after ph5)
        BAR1; MFMA16(1); BAR1;

        RDA(32768, 2);
        if (s2) SH(49152, b3p, 1);
        BAR1; MFMA16(2); BAR1;

        RDA(32768, 3);
        BAR1; MFMA16(3);
        if (s2) { asm volatile("s_waitcnt vmcnt(4)" ::: "memory"); }   // buf0=kt 2t+2 landed
        BAR1;
    }

    // epilogue: e tile + per-(row, 64-col-block) softmax partials
    float* eb = e + (size_t)b * M_ * N_;
    const int grows = (int)gridDim.z * M_;
    const int growbase = b * M_ + m0 + wm;
    const int nb = (n0 + wn) >> 6;  // 0..31
    float* pm = pmax + (size_t)nb * grows + growbase;
    float* ps = psum + (size_t)nb * grows + growbase;

#pragma unroll
    for (int i = 0; i < 8; ++i) {
#pragma unroll
        for (int r = 0; r < 4; ++r) {
            const float v0 = acc[i][0][r], v1 = acc[i][1][r];
            const float v2 = acc[i][2][r], v3 = acc[i][3][r];
            float mrow = fmaxf(fmaxf(v0, v1), fmaxf(v2, v3));
#pragma unroll
            for (int s = 1; s < 16; s <<= 1) mrow = fmaxf(mrow, __shfl_xor(mrow, s, 64));
            float srow_ = __expf(v0 - mrow) + __expf(v1 - mrow)
                        + __expf(v2 - mrow) + __expf(v3 - mrow);
#pragma unroll
            for (int s = 1; s < 16; s <<= 1) srow_ += __shfl_xor(srow_, s, 64);
            const int lrow = i * 16 + quad * 4 + r;
            if (r16 == 0) { pm[lrow] = mrow; ps[lrow] = srow_; }
            const size_t ebase = (size_t)(m0 + wm + lrow) * N_ + n0 + wn + r16;
#pragma unroll
            for (int j = 0; j < 4; ++j) eb[ebase + j * 16] = acc[i][j][r];
        }
    }
}

// ---------------- combine partials -> mx, inv ----------------
__global__ __launch_bounds__(256) void k_combine(const float* __restrict__ pmax,
                                                 const float* __restrict__ psum,
                                                 float* __restrict__ mx,
                                                 float* __restrict__ inv, int rows) {
    const int r = blockIdx.x * 256 + threadIdx.x;
    float m = -3.4e38f;
#pragma unroll
    for (int nb = 0; nb < 32; ++nb) m = fmaxf(m, pmax[(size_t)nb * rows + r]);
    float s = 0.f;
#pragma unroll
    for (int nb = 0; nb < 32; ++nb)
        s += psum[(size_t)nb * rows + r] * __expf(pmax[(size_t)nb * rows + r] - m);
    mx[r] = m;
    inv[r] = 1.0f / s;
}

// ---------------- transposed softmax: pT[b][n][m] = bf16(exp(e[b][m][n]-mx)*inv) ----------------
__global__ __launch_bounds__(256) void k_texp(const float* __restrict__ e,
                                              const float* __restrict__ mx,
                                              const float* __restrict__ inv,
                                              uint16_t* __restrict__ pT) {
    const int b = blockIdx.z, m0 = blockIdx.x * 64, n0 = blockIdx.y * 64;
    __shared__ float tile[64 * 65];
    const int t = threadIdx.x;
    const float* eb = e + (size_t)b * M_ * N_;
#pragma unroll
    for (int q = 0; q < 4; ++q) {
        const int row = q * 16 + (t >> 4);
        const int c4 = (t & 15) * 4;
        float4 v = *(const float4*)&eb[(size_t)(m0 + row) * N_ + n0 + c4];
        const float mv = mx[b * M_ + m0 + row];
        const float iv = inv[b * M_ + m0 + row];
        tile[row * 65 + c4 + 0] = __expf(v.x - mv) * iv;
        tile[row * 65 + c4 + 1] = __expf(v.y - mv) * iv;
        tile[row * 65 + c4 + 2] = __expf(v.z - mv) * iv;
        tile[row * 65 + c4 + 3] = __expf(v.w - mv) * iv;
    }
    __syncthreads();
    uint16_t* pb = pT + (size_t)b * N_ * M_;
#pragma unroll
    for (int q = 0; q < 2; ++q) {
        const int n = q * 32 + (t >> 3);
        const int mc = (t & 7) * 8;
        us8 o;
#pragma unroll
        for (int k = 0; k < 8; ++k) o[k] = f2b(tile[(mc + k) * 65 + n]);
        *(us8*)&pb[(size_t)(n0 + n) * M_ + m0 + mc] = o;
    }
}

// ---------------- transpose x: xt[b][d][m] = bf16(x[b][m][d]) ----------------
__global__ __launch_bounds__(256) void k_tx(const float* __restrict__ x,
                                            uint16_t* __restrict__ xt) {
    const int b = blockIdx.z, m0 = blockIdx.x * 64, d0 = blockIdx.y * 64;
    __shared__ float tile[64 * 65];
    const int t = threadIdx.x;
    const float* xb = x + (size_t)b * M_ * D_;
#pragma unroll
    for (int q = 0; q < 4; ++q) {
        const int row = q * 16 + (t >> 4);
        const int c4 = (t & 15) * 4;
        float4 v = *(const float4*)&xb[(size_t)(m0 + row) * D_ + d0 + c4];
        tile[row * 65 + c4 + 0] = v.x;
        tile[row * 65 + c4 + 1] = v.y;
        tile[row * 65 + c4 + 2] = v.z;
        tile[row * 65 + c4 + 3] = v.w;
    }
    __syncthreads();
    uint16_t* xtb = xt + (size_t)b * D_ * M_;
#pragma unroll
    for (int q = 0; q < 2; ++q) {
        const int d = q * 32 + (t >> 3);
        const int mc = (t & 7) * 8;
        us8 o;
#pragma unroll
        for (int k = 0; k < 8; ++k) o[k] = f2b(tile[(mc + k) * 65 + d]);
        *(us8*)&xtb[(size_t)(d0 + d) * M_ + m0 + mc] = o;
    }
}

// ---------------- GEMM2: out[b][n][d] = sum_m pT[b][n][m] * xt[b][d][m] ----------------
__global__ __launch_bounds__(256) void k_gemm2(const uint16_t* __restrict__ pT,
                                               const uint16_t* __restrict__ xt,
                                               float* __restrict__ out) {
    const int b = blockIdx.z;
    const int n0 = blockIdx.x * 128;
    const int d0 = blockIdx.y * 128;
    __shared__ __align__(16) uint16_t lds[16384];  // 2 tiles of 128x64 bf16

    const int tid = threadIdx.x;
    const int lane = tid & 63;
    const int wid = tid >> 6;
    const int wn = (wid & 1) * 64;
    const int wd = (wid >> 1) * 64;
    const int quad = lane >> 4;
    const int r16 = lane & 15;

    const uint16_t* srcA = pT + ((size_t)b * N_ + n0) * M_;
    const uint16_t* srcB = xt + ((size_t)b * D_ + d0) * M_;

    f32x4 acc[4][4];
#pragma unroll
    for (int i = 0; i < 4; ++i)
#pragma unroll
        for (int j = 0; j < 4; ++j) acc[i][j] = (f32x4){0.f, 0.f, 0.f, 0.f};

    for (int kt = 0; kt < M_ / 64; ++kt) {
#pragma unroll
        for (int c = 0; c < 8; ++c) {
            const int offbase = c * 2048 + wid * 512;
            const int tile = offbase >> 13;             // 8192 elems per tile
            const int o = (offbase & 8191) + lane * 8;
            const int row = o >> 6;                     // 64 elems per row
            const int gp = (o & 63) >> 3;               // granule position 0..7
            const int gd = gp ^ (row & 7);              // data granule (swizzle)
            const uint16_t* sp = tile ? srcB : srcA;
            gld16(sp + (size_t)row * M_ + kt * 64 + gd * 8, &lds[offbase]);
        }
        __syncthreads();

#pragma unroll
        for (int h = 0; h < 2; ++h) {                   // two K=32 halves
            const int p = (h * 4 + quad) ^ (r16 & 7);   // swizzled granule pos
            bf16x8 a[4], bbr[4];
#pragma unroll
            for (int i = 0; i < 4; ++i) {
                a[i]   = *(const bf16x8*)&lds[(wn + i * 16 + r16) * 64 + p * 8];
                bbr[i] = *(const bf16x8*)&lds[8192 + (wd + i * 16 + r16) * 64 + p * 8];
            }
#pragma unroll
            for (int i = 0; i < 4; ++i)
#pragma unroll
                for (int j = 0; j < 4; ++j)
                    acc[i][j] = __builtin_amdgcn_mfma_f32_16x16x32_bf16(a[i], bbr[j], acc[i][j], 0, 0, 0);
        }
        __syncthreads();
    }

    float* ob = out + (size_t)b * N_ * D_;
#pragma unroll
    for (int i = 0; i < 4; ++i) {
        const int rbase = n0 + wn + i * 16 + quad * 4;
#pragma unroll
        for (int j = 0; j < 4; ++j) {
            const int col = d0 + wd + j * 16 + r16;
#pragma unroll
            for (int r = 0; r < 4; ++r)
                ob[(size_t)(rbase + r) * D_ + col] = acc[i][j][r];
        }
    }
}

extern "C" void kernel_launch(void* const* d_in, const int* in_sizes, int n_in,
                              void* d_out, int out_size, void* d_ws, size_t ws_size,
                              hipStream_t stream) {
    const float* x = (const float*)d_in[0];
    const float* y = (const float*)d_in[1];
    float* out = (float*)d_out;
    char* ws = (char*)d_ws;

    // Per-chunk footprint (g batches), with overlays: exactly 32g MiB.
    //   [xh 4g][xl 4g][yh 4g][yl 4g][e 16g]
    // After gemm1 the split region is dead:
    //   stats (mx,inv) overlay xh; xt overlays xl; pT overlays yh+yl.
    const size_t MiB = 1024 * 1024;
    int g = 8;
    while (g > 1 && (size_t)g * 32 * MiB > ws_size) g >>= 1;
    if ((size_t)g * 32 * MiB > ws_size) return;  // ws too small: clean fail (diagnostic)

    const size_t T = (size_t)g * M_ * D_ * 2;  // one split tensor (4g MiB)
    uint16_t* xh = (uint16_t*)(ws + 0 * T);
    uint16_t* xl = (uint16_t*)(ws + 1 * T);
    uint16_t* yh = (uint16_t*)(ws + 2 * T);
    uint16_t* yl = (uint16_t*)(ws + 3 * T);
    float*    e  = (float*)(ws + 4 * T);
    float*    mx = (float*)(ws);               // overlays xh (dead after gemm1)
    float*    inv = mx + (size_t)g * M_;
    uint16_t* xt = xl;                          // overlays xl (dead after gemm1)
    uint16_t* pT = yh;                          // overlays yh+yl (dead after gemm1)

    // softmax partials live in the tail of d_out: d_out is dead until gemm2,
    // and only the LAST chunk's gemm2 covers the tail — after combine read it.
    const size_t pelems = (size_t)32 * g * M_;
    float* pmax = (float*)d_out + (size_t)B_ * N_ * D_ - 2 * pelems;
    float* psum = pmax + pelems;

    for (int c0 = 0; c0 < B_; c0 += g) {
        const float* xc = x + (size_t)c0 * M_ * D_;
        const float* yc = y + (size_t)c0 * N_ * D_;
        float* oc = out + (size_t)c0 * N_ * D_;

        hipLaunchKernelGGL(k_split, dim3((g * M_ * D_) / (256 * 4)), dim3(256), 0, stream,
                           xc, yc, xh, xl, yh, yl);
        hipLaunchKernelGGL(k_gemm1, dim3(M_ / 256, N_ / 256, g), dim3(512), 0, stream,
                           xh, xl, yh, yl, e, pmax, psum);
        hipLaunchKernelGGL(k_combine, dim3((g * M_) / 256), dim3(256), 0, stream,
                           pmax, psum, mx, inv, g * M_);
        hipLaunchKernelGGL(k_texp, dim3(M_ / 64, N_ / 64, g), dim3(256), 0, stream,
                           e, mx, inv, pT);
        hipLaunchKernelGGL(k_tx, dim3(M_ / 64, D_ / 64, g), dim3(256), 0, stream, xc, xt);
        hipLaunchKernelGGL(k_gemm2, dim3(N_ / 128, D_ / 128, g), dim3(256), 0, stream,
                           pT, xt, oc);
    }
}

// Round 3
// 498.858 us; speedup vs baseline: 1.0323x; 1.0323x over previous
//
#include <hip/hip_runtime.h>
#include <hip/hip_bf16.h>
#include <stdint.h>

#define B_ 8
#define M_ 2048
#define N_ 2048
#define D_ 1024

typedef __bf16 bf16x8 __attribute__((ext_vector_type(8)));
typedef float f32x4 __attribute__((ext_vector_type(4)));
typedef uint16_t us4 __attribute__((ext_vector_type(4)));
typedef uint16_t us8 __attribute__((ext_vector_type(8)));

__device__ __forceinline__ uint16_t f2b(float f) {
    uint32_t u = __float_as_uint(f);
    return (uint16_t)((u + 0x7FFFu + ((u >> 16) & 1u)) >> 16);
}
__device__ __forceinline__ float b2f(uint16_t h) {
    return __uint_as_float(((uint32_t)h) << 16);
}

__device__ __forceinline__ void gld16(const uint16_t* g, const uint16_t* l) {
    __builtin_amdgcn_global_load_lds(
        (const __attribute__((address_space(1))) uint32_t*)g,
        (__attribute__((address_space(3))) uint32_t*)l,
        16, 0, 0);
}

// ---------------- split x,y into bf16 hi/lo ----------------
__global__ __launch_bounds__(256) void k_split(const float* __restrict__ x,
                                               const float* __restrict__ y,
                                               uint16_t* __restrict__ xh, uint16_t* __restrict__ xl,
                                               uint16_t* __restrict__ yh, uint16_t* __restrict__ yl) {
    const int i = (blockIdx.x * 256 + threadIdx.x) * 4;
    float4 vx = *(const float4*)(x + i);
    float4 vy = *(const float4*)(y + i);
    float fx[4] = {vx.x, vx.y, vx.z, vx.w};
    float fy[4] = {vy.x, vy.y, vy.z, vy.w};
    us4 hx, lx, hy, ly;
#pragma unroll
    for (int k = 0; k < 4; ++k) {
        uint16_t h = f2b(fx[k]);
        hx[k] = h; lx[k] = f2b(fx[k] - b2f(h));
        uint16_t g = f2b(fy[k]);
        hy[k] = g; ly[k] = f2b(fy[k] - b2f(g));
    }
    *(us4*)(xh + i) = hx;
    *(us4*)(xl + i) = lx;
    *(us4*)(yh + i) = hy;
    *(us4*)(yl + i) = ly;
}

// ---------------- GEMM1: e[b][m][n] = xh.yh^T + xh.yl^T + xl.yh^T ----------------
// r1 data layout (256x256 tile, 8 waves 2Mx4N, BK=32, 4 tensor tiles/buffer,
// 2 LDS buffers = 128KB, verified conflict-free granule swizzles) with a new
// low-barrier register-double-buffered schedule:
//   - A-fragments ping-pong between 2 register sets; each window issues the
//     NEXT window's ds_reads before its own MFMA cluster, so the LDS drain
//     hides under MFMA (compiler emits counted lgkmcnt(4) gates).
//   - Full next-tile staging (8 gld16/wave) issued in W0 -> ~2-window lead;
//     the boundary vmcnt(0) is normally already satisfied.
//   - Only 2 s_barriers per K-step: {vmcnt(0); barrier} publishing buf'
//     before W3 reads it, and a tile-start barrier after W3 making the
//     overwrite of buf (by the next step's W0 staging) safe. All fragment
//     reads of a buffer are lgkm-complete before each wave's last MFMA
//     cluster, which precedes that barrier (WAR closed).
// Epilogue (verbatim r1): e tile + per-(row, 64-col) softmax partials.
#define SBAR0 __builtin_amdgcn_sched_barrier(0)
#define LD8(off) (*(const bf16x8*)&lds[off])
#define RDB(bo)                                                        \
    _Pragma("unroll") for (int j = 0; j < 4; ++j) {                    \
        bh[j] = LD8((bo) + bbase + j * 512);                           \
        bl[j] = LD8((bo) + bbase + 8192 + j * 512);                    \
    }
#define RDA(H, L, bo, q)                                               \
    H[0] = LD8((bo) + abase + ((q)*2) * 512);                          \
    H[1] = LD8((bo) + abase + ((q)*2 + 1) * 512);                      \
    L[0] = LD8((bo) + abase + 8192 + ((q)*2) * 512);                   \
    L[1] = LD8((bo) + abase + 8192 + ((q)*2 + 1) * 512);
#define MMQ(H, L, q)                                                   \
    __builtin_amdgcn_s_setprio(1);                                     \
    _Pragma("unroll") for (int ii = 0; ii < 2; ++ii)                   \
    _Pragma("unroll") for (int j = 0; j < 4; ++j) {                    \
        acc[(q)*2 + ii][j] = __builtin_amdgcn_mfma_f32_16x16x32_bf16(  \
            H[ii], bh[j], acc[(q)*2 + ii][j], 0, 0, 0);                \
        acc[(q)*2 + ii][j] = __builtin_amdgcn_mfma_f32_16x16x32_bf16(  \
            H[ii], bl[j], acc[(q)*2 + ii][j], 0, 0, 0);                \
        acc[(q)*2 + ii][j] = __builtin_amdgcn_mfma_f32_16x16x32_bf16(  \
            L[ii], bh[j], acc[(q)*2 + ii][j], 0, 0, 0);                \
    }                                                                  \
    __builtin_amdgcn_s_setprio(0);

__global__ __launch_bounds__(512, 2) void k_gemm1(const uint16_t* __restrict__ xh,
                                                  const uint16_t* __restrict__ xl,
                                                  const uint16_t* __restrict__ yh,
                                                  const uint16_t* __restrict__ yl,
                                                  float* __restrict__ e,
                                                  float* __restrict__ pmax,
                                                  float* __restrict__ psum) {
    const int b = blockIdx.z;
    const int m0 = blockIdx.x * 256;
    const int n0 = blockIdx.y * 256;
    __shared__ __align__(16) uint16_t lds[65536];  // 2 buf x 4 tiles x (256x32)

    const int tid = threadIdx.x;
    const int lane = tid & 63;
    const int wid = tid >> 6;             // 8 waves: 2 (m) x 4 (n)
    const int wm = (wid >> 2) * 128;
    const int wn = (wid & 3) * 64;
    const int quad = lane >> 4;
    const int r16 = lane & 15;
    const int swz8 = (quad ^ ((r16 >> 1) & 3)) * 8;

    // staging (verbatim r1): chunk c -> tensor c>>1, rows (c&1)*128 + wid*16
    // + lane/4, granule lane&3 stored at pos ^((row>>1)&3)
    const int base_row = wid * 16 + (lane >> 2);
    const int gd8 = ((lane & 3) ^ ((lane >> 3) & 3)) * 8;
    const uint16_t* gp[4];
    gp[0] = xh + ((size_t)b * M_ + m0 + base_row) * D_ + gd8;
    gp[1] = xl + ((size_t)b * M_ + m0 + base_row) * D_ + gd8;
    gp[2] = yh + ((size_t)b * N_ + n0 + base_row) * D_ + gd8;
    gp[3] = yl + ((size_t)b * N_ + n0 + base_row) * D_ + gd8;
    const int ldsW = wid * 512;

    const int abase = (wm + r16) * 32 + swz8;          // xh tile @0, xl @+8192
    const int bbase = 16384 + (wn + r16) * 32 + swz8;  // yh @16384, yl @+8192

    auto STAGE = [&](int dst, int ktn) {
#pragma unroll
        for (int c = 0; c < 8; ++c)
            gld16(gp[c >> 1] + (size_t)(c & 1) * (128 * D_) + ktn * 32,
                  &lds[dst + c * 4096 + ldsW]);
    };

    f32x4 acc[8][4];
#pragma unroll
    for (int i = 0; i < 8; ++i)
#pragma unroll
        for (int j = 0; j < 4; ++j) acc[i][j] = (f32x4){0.f, 0.f, 0.f, 0.f};

    bf16x8 bh[4], bl[4];
    bf16x8 a0h[2], a0l[2];   // register set 0 (itile pairs 0,2 and next-tile 0)
    bf16x8 a1h[2], a1l[2];   // register set 1 (itile pairs 1,3)

    // prologue: stage tile 0, publish, prime B + pair0 into set 0
    STAGE(0, 0);
    asm volatile("s_waitcnt vmcnt(0)" ::: "memory");
    SBAR0; __builtin_amdgcn_s_barrier(); SBAR0;
    RDB(0); RDA(a0h, a0l, 0, 0);

    for (int t = 0; t < 32; ++t) {
        const int bo = (t & 1) << 15;
        const int nbo = bo ^ 32768;
        const bool more = t < 31;

        // W0: stage tile t+1 into buf', read pair1 -> set1, MFMA pair0 (set0)
        if (more) STAGE(nbo, t + 1);
        RDA(a1h, a1l, bo, 1);
        SBAR0;
        MMQ(a0h, a0l, 0);
        SBAR0;

        // W1: read pair2 -> set0, MFMA pair1 (set1)
        RDA(a0h, a0l, bo, 2);
        SBAR0;
        MMQ(a1h, a1l, 1);
        SBAR0;

        // W2: read pair3 -> set1, MFMA pair2 (set0)
        RDA(a1h, a1l, bo, 3);
        SBAR0;
        MMQ(a0h, a0l, 2);
        SBAR0;

        // boundary: buf' staged ~2 windows ago -> vmcnt(0) normally free
        asm volatile("s_waitcnt vmcnt(0)" ::: "memory");
        SBAR0; __builtin_amdgcn_s_barrier(); SBAR0;

        // W3: read next tile's pair0 -> set0, MFMA pair3 (set1), then next B
        if (more) { RDA(a0h, a0l, nbo, 0); }
        SBAR0;
        MMQ(a1h, a1l, 3);
        SBAR0;
        if (more) {
            RDB(nbo);                       // after last use of bh/bl(t)
            SBAR0; __builtin_amdgcn_s_barrier(); SBAR0;  // tile-start: buf reads done
        }
    }

    // epilogue (verbatim r1): e tile + per-(row, 64-col-block) softmax partials
    float* eb = e + (size_t)b * M_ * N_;
    const int grows = (int)gridDim.z * M_;
    const int growbase = b * M_ + m0 + wm;
    const int nb = (n0 + wn) >> 6;  // 0..31
    float* pm = pmax + (size_t)nb * grows + growbase;
    float* ps = psum + (size_t)nb * grows + growbase;

#pragma unroll
    for (int i = 0; i < 8; ++i) {
#pragma unroll
        for (int r = 0; r < 4; ++r) {
            const float v0 = acc[i][0][r], v1 = acc[i][1][r];
            const float v2 = acc[i][2][r], v3 = acc[i][3][r];
            float mrow = fmaxf(fmaxf(v0, v1), fmaxf(v2, v3));
#pragma unroll
            for (int s = 1; s < 16; s <<= 1) mrow = fmaxf(mrow, __shfl_xor(mrow, s, 64));
            float srow_ = __expf(v0 - mrow) + __expf(v1 - mrow)
                        + __expf(v2 - mrow) + __expf(v3 - mrow);
#pragma unroll
            for (int s = 1; s < 16; s <<= 1) srow_ += __shfl_xor(srow_, s, 64);
            const int lrow = i * 16 + quad * 4 + r;
            if (r16 == 0) { pm[lrow] = mrow; ps[lrow] = srow_; }
            const size_t ebase = (size_t)(m0 + wm + lrow) * N_ + n0 + wn + r16;
#pragma unroll
            for (int j = 0; j < 4; ++j) eb[ebase + j * 16] = acc[i][j][r];
        }
    }
}

// ---------------- combine partials -> mx, inv ----------------
__global__ __launch_bounds__(256) void k_combine(const float* __restrict__ pmax,
                                                 const float* __restrict__ psum,
                                                 float* __restrict__ mx,
                                                 float* __restrict__ inv, int rows) {
    const int r = blockIdx.x * 256 + threadIdx.x;
    float m = -3.4e38f;
#pragma unroll
    for (int nb = 0; nb < 32; ++nb) m = fmaxf(m, pmax[(size_t)nb * rows + r]);
    float s = 0.f;
#pragma unroll
    for (int nb = 0; nb < 32; ++nb)
        s += psum[(size_t)nb * rows + r] * __expf(pmax[(size_t)nb * rows + r] - m);
    mx[r] = m;
    inv[r] = 1.0f / s;
}

// ---------------- transposed softmax: pT[b][n][m] = bf16(exp(e[b][m][n]-mx)*inv) ----------------
__global__ __launch_bounds__(256) void k_texp(const float* __restrict__ e,
                                              const float* __restrict__ mx,
                                              const float* __restrict__ inv,
                                              uint16_t* __restrict__ pT) {
    const int b = blockIdx.z, m0 = blockIdx.x * 64, n0 = blockIdx.y * 64;
    __shared__ float tile[64 * 65];
    const int t = threadIdx.x;
    const float* eb = e + (size_t)b * M_ * N_;
#pragma unroll
    for (int q = 0; q < 4; ++q) {
        const int row = q * 16 + (t >> 4);
        const int c4 = (t & 15) * 4;
        float4 v = *(const float4*)&eb[(size_t)(m0 + row) * N_ + n0 + c4];
        const float mv = mx[b * M_ + m0 + row];
        const float iv = inv[b * M_ + m0 + row];
        tile[row * 65 + c4 + 0] = __expf(v.x - mv) * iv;
        tile[row * 65 + c4 + 1] = __expf(v.y - mv) * iv;
        tile[row * 65 + c4 + 2] = __expf(v.z - mv) * iv;
        tile[row * 65 + c4 + 3] = __expf(v.w - mv) * iv;
    }
    __syncthreads();
    uint16_t* pb = pT + (size_t)b * N_ * M_;
#pragma unroll
    for (int q = 0; q < 2; ++q) {
        const int n = q * 32 + (t >> 3);
        const int mc = (t & 7) * 8;
        us8 o;
#pragma unroll
        for (int k = 0; k < 8; ++k) o[k] = f2b(tile[(mc + k) * 65 + n]);
        *(us8*)&pb[(size_t)(n0 + n) * M_ + m0 + mc] = o;
    }
}

// ---------------- transpose x: xt[b][d][m] = bf16(x[b][m][d]) ----------------
__global__ __launch_bounds__(256) void k_tx(const float* __restrict__ x,
                                            uint16_t* __restrict__ xt) {
    const int b = blockIdx.z, m0 = blockIdx.x * 64, d0 = blockIdx.y * 64;
    __shared__ float tile[64 * 65];
    const int t = threadIdx.x;
    const float* xb = x + (size_t)b * M_ * D_;
#pragma unroll
    for (int q = 0; q < 4; ++q) {
        const int row = q * 16 + (t >> 4);
        const int c4 = (t & 15) * 4;
        float4 v = *(const float4*)&xb[(size_t)(m0 + row) * D_ + d0 + c4];
        tile[row * 65 + c4 + 0] = v.x;
        tile[row * 65 + c4 + 1] = v.y;
        tile[row * 65 + c4 + 2] = v.z;
        tile[row * 65 + c4 + 3] = v.w;
    }
    __syncthreads();
    uint16_t* xtb = xt + (size_t)b * D_ * M_;
#pragma unroll
    for (int q = 0; q < 2; ++q) {
        const int d = q * 32 + (t >> 3);
        const int mc = (t & 7) * 8;
        us8 o;
#pragma unroll
        for (int k = 0; k < 8; ++k) o[k] = f2b(tile[(mc + k) * 65 + d]);
        *(us8*)&xtb[(size_t)(d0 + d) * M_ + m0 + mc] = o;
    }
}

// ---------------- GEMM2: out[b][n][d] = sum_m pT[b][n][m] * xt[b][d][m] ----------------
__global__ __launch_bounds__(256) void k_gemm2(const uint16_t* __restrict__ pT,
                                               const uint16_t* __restrict__ xt,
                                               float* __restrict__ out) {
    const int b = blockIdx.z;
    const int n0 = blockIdx.x * 128;
    const int d0 = blockIdx.y * 128;
    __shared__ __align__(16) uint16_t lds[16384];  // 2 tiles of 128x64 bf16

    const int tid = threadIdx.x;
    const int lane = tid & 63;
    const int wid = tid >> 6;
    const int wn = (wid & 1) * 64;
    const int wd = (wid >> 1) * 64;
    const int quad = lane >> 4;
    const int r16 = lane & 15;

    const uint16_t* srcA = pT + ((size_t)b * N_ + n0) * M_;
    const uint16_t* srcB = xt + ((size_t)b * D_ + d0) * M_;

    f32x4 acc[4][4];
#pragma unroll
    for (int i = 0; i < 4; ++i)
#pragma unroll
        for (int j = 0; j < 4; ++j) acc[i][j] = (f32x4){0.f, 0.f, 0.f, 0.f};

    for (int kt = 0; kt < M_ / 64; ++kt) {
#pragma unroll
        for (int c = 0; c < 8; ++c) {
            const int offbase = c * 2048 + wid * 512;
            const int tile = offbase >> 13;             // 8192 elems per tile
            const int o = (offbase & 8191) + lane * 8;
            const int row = o >> 6;                     // 64 elems per row
            const int gp = (o & 63) >> 3;               // granule position 0..7
            const int gd = gp ^ (row & 7);              // data granule (swizzle)
            const uint16_t* sp = tile ? srcB : srcA;
            gld16(sp + (size_t)row * M_ + kt * 64 + gd * 8, &lds[offbase]);
        }
        __syncthreads();

#pragma unroll
        for (int h = 0; h < 2; ++h) {                   // two K=32 halves
            const int p = (h * 4 + quad) ^ (r16 & 7);   // swizzled granule pos
            bf16x8 a[4], bbr[4];
#pragma unroll
            for (int i = 0; i < 4; ++i) {
                a[i]   = *(const bf16x8*)&lds[(wn + i * 16 + r16) * 64 + p * 8];
                bbr[i] = *(const bf16x8*)&lds[8192 + (wd + i * 16 + r16) * 64 + p * 8];
            }
#pragma unroll
            for (int i = 0; i < 4; ++i)
#pragma unroll
                for (int j = 0; j < 4; ++j)
                    acc[i][j] = __builtin_amdgcn_mfma_f32_16x16x32_bf16(a[i], bbr[j], acc[i][j], 0, 0, 0);
        }
        __syncthreads();
    }

    float* ob = out + (size_t)b * N_ * D_;
#pragma unroll
    for (int i = 0; i < 4; ++i) {
        const int rbase = n0 + wn + i * 16 + quad * 4;
#pragma unroll
        for (int j = 0; j < 4; ++j) {
            const int col = d0 + wd + j * 16 + r16;
#pragma unroll
            for (int r = 0; r < 4; ++r)
                ob[(size_t)(rbase + r) * D_ + col] = acc[i][j][r];
        }
    }
}

extern "C" void kernel_launch(void* const* d_in, const int* in_sizes, int n_in,
                              void* d_out, int out_size, void* d_ws, size_t ws_size,
                              hipStream_t stream) {
    const float* x = (const float*)d_in[0];
    const float* y = (const float*)d_in[1];
    float* out = (float*)d_out;
    char* ws = (char*)d_ws;

    // Per-chunk footprint (g batches), with overlays: exactly 32g MiB.
    //   [xh 4g][xl 4g][yh 4g][yl 4g][e 16g]
    // After gemm1 the split region is dead:
    //   stats (mx,inv) overlay xh; xt overlays xl; pT overlays yh+yl.
    const size_t MiB = 1024 * 1024;
    int g = 8;
    while (g > 1 && (size_t)g * 32 * MiB > ws_size) g >>= 1;
    if ((size_t)g * 32 * MiB > ws_size) return;  // ws too small: clean fail (diagnostic)

    const size_t T = (size_t)g * M_ * D_ * 2;  // one split tensor (4g MiB)
    uint16_t* xh = (uint16_t*)(ws + 0 * T);
    uint16_t* xl = (uint16_t*)(ws + 1 * T);
    uint16_t* yh = (uint16_t*)(ws + 2 * T);
    uint16_t* yl = (uint16_t*)(ws + 3 * T);
    float*    e  = (float*)(ws + 4 * T);
    float*    mx = (float*)(ws);               // overlays xh (dead after gemm1)
    float*    inv = mx + (size_t)g * M_;
    uint16_t* xt = xl;                          // overlays xl (dead after gemm1)
    uint16_t* pT = yh;                          // overlays yh+yl (dead after gemm1)

    // softmax partials live in the tail of d_out: d_out is dead until gemm2,
    // and only the LAST chunk's gemm2 covers the tail — after combine read it.
    const size_t pelems = (size_t)32 * g * M_;
    float* pmax = (float*)d_out + (size_t)B_ * N_ * D_ - 2 * pelems;
    float* psum = pmax + pelems;

    for (int c0 = 0; c0 < B_; c0 += g) {
        const float* xc = x + (size_t)c0 * M_ * D_;
        const float* yc = y + (size_t)c0 * N_ * D_;
        float* oc = out + (size_t)c0 * N_ * D_;

        hipLaunchKernelGGL(k_split, dim3((g * M_ * D_) / (256 * 4)), dim3(256), 0, stream,
                           xc, yc, xh, xl, yh, yl);
        hipLaunchKernelGGL(k_gemm1, dim3(M_ / 256, N_ / 256, g), dim3(512), 0, stream,
                           xh, xl, yh, yl, e, pmax, psum);
        hipLaunchKernelGGL(k_combine, dim3((g * M_) / 256), dim3(256), 0, stream,
                           pmax, psum, mx, inv, g * M_);
        hipLaunchKernelGGL(k_texp, dim3(M_ / 64, N_ / 64, g), dim3(256), 0, stream,
                           e, mx, inv, pT);
        hipLaunchKernelGGL(k_tx, dim3(M_ / 64, D_ / 64, g), dim3(256), 0, stream, xc, xt);
        hipLaunchKernelGGL(k_gemm2, dim3(N_ / 128, D_ / 128, g), dim3(256), 0, stream,
                           pT, xt, oc);
    }
}